// Round 5
// baseline (932.032 us; speedup 1.0000x reference)
//
#include <hip/hip_runtime.h>
#include <math.h>

// Problem constants
#define NB  262144   // batch
#define SD  128      // STATE_DIM
#define HID 256      // HIDDEN
#define AD  8        // ACTION_DIM

typedef float v2f __attribute__((ext_vector_type(2)));

// d_ws layout (floats)
#define W1T_OFF 0                       // [SD][HID]   W1T[k*HID+j] = W1[j*SD+k]
#define W2T_OFF (SD*HID)                // [HID][HID]  32768
#define W3P_OFF (W2T_OFF + HID*HID)     // [HID][AD] float2 pairs (u,s): 98304, 4096 floats
#define B1_OFF  (W3P_OFF + HID*2*AD)    // 102400
#define B2_OFF  (B1_OFF + HID)          // 102656
#define B3P_OFF (B2_OFF + HID)          // 102912, [AD] float2 pairs
#define WS_FLOATS (B3P_OFF + 2*AD)      // 102928 floats = 411,712 bytes

__global__ __launch_bounds__(256) void prep_weights(
    const float* __restrict__ W1, const float* __restrict__ b1,
    const float* __restrict__ W2, const float* __restrict__ b2,
    const float* __restrict__ W3, const float* __restrict__ b3,
    float* __restrict__ ws) {
  int stride = gridDim.x * blockDim.x;
  for (int i = blockIdx.x * blockDim.x + threadIdx.x; i < WS_FLOATS; i += stride) {
    float v;
    if (i < W2T_OFF) {                       // W1T
      int k = i >> 8, j = i & 255;
      v = W1[j * SD + k];
    } else if (i < W3P_OFF) {                // W2T
      int t = i - W2T_OFF;
      int k = t >> 8, j = t & 255;
      v = W2[j * HID + k];
    } else if (i < B1_OFF) {                 // W3P[k][a] = (W3[a][k], W3[a+8][k])
      int t = i - W3P_OFF;
      int k = t >> 4, a = (t >> 1) & 7, h = t & 1;
      v = W3[(a + 8 * h) * HID + k];
    } else if (i < B2_OFF) {
      v = b1[i - B1_OFF];
    } else if (i < B3P_OFF) {
      v = b2[i - B2_OFF];
    } else {                                 // B3P[a] = (b3[a], b3[a+8])
      int t = i - B3P_OFF;
      v = b3[(t >> 1) + 8 * (t & 1)];
    }
    ws[i] = v;
  }
}

// R9 theory: the pinned 60% VALUBusy / 806 us across R4..R8 is L2 WEIGHT
// SERVING. Every wave streamed the full 410 KB of W1T/W2T/W3P from L2:
// 32768 waves x 410 KB = 13.4 GB of L2 reads (~50% of aggregate L2 BW, all
// CUs of an XCD hitting the same 4 MB slice) -> queueing-inflated latency
// that ~3.5 resident waves/SIMD cannot hide. Occupancy/TLP knobs (R7/R8)
// were no-ops because the stall source is a SHARED resource.
//
// Fix: column-split. Block = 128 threads (2 waves) owns 16 rows; wave w
// computes output cols [w*128, w*128+128) of layers 1-2, so each wave reads
// only HALF of W1T/W2T -> total L2 weight traffic 13.4 -> 6.7 GB. Per-wave
// fmac count unchanged. Shared h buffer [16][256] = 16 KiB/block (10
// blocks/CU possible), XOR float4-group swizzle (g ^ (row&7)) as before.
// Cross-wave h dependency -> 3 __syncthreads() per block (cheap, 2 waves).
// Layer 3: wave w handles rows w*8..w*8+7, unchanged math.
__global__ __launch_bounds__(128, 2) void actor_fused(
    const float* __restrict__ state, const float* __restrict__ eps,
    const float* __restrict__ ws, int* __restrict__ out) {
  __shared__ float s_h[16][256];   // 16,384 B per block (block-shared now)

  const int tid  = threadIdx.x;
  const int lane = tid & 63;
  const int wvu  = __builtin_amdgcn_readfirstlane(tid >> 6);  // 0..1, uniform
  const int wl   = wvu * 64 + lane;          // this thread's col-pair index
  const long brow = (long)blockIdx.x * 16;   // block's first row

  const v2f* __restrict__ W1T2 = (const v2f*)(ws + W1T_OFF);  // [SD][128] pairs
  const v2f* __restrict__ W2T2 = (const v2f*)(ws + W2T_OFF);  // [HID][128] pairs
  const v2f* __restrict__ W3P  = (const v2f*)(ws + W3P_OFF);  // [HID][8]

  const float* __restrict__ xbase = state + brow * SD;   // block-uniform pointer

  // ---- layer 1: h1 = relu(x @ W1^T + b1), K = 128. This wave: cols 2*wl, 2*wl+1.
  v2f acc[16];
  #pragma unroll
  for (int r = 0; r < 16; ++r) acc[r] = (v2f){0.f, 0.f};

  #pragma unroll 2
  for (int k0 = 0; k0 < SD; k0 += 4) {
    const int wb = k0 * 128 + wl;
    v2f w0 = W1T2[wb];
    v2f w1 = W1T2[wb + 128];
    v2f w2 = W1T2[wb + 256];
    v2f w3 = W1T2[wb + 384];
    #pragma unroll
    for (int rg = 0; rg < 2; ++rg) {
      float4 xv[8];
      #pragma unroll
      for (int r = 0; r < 8; ++r)                         // uniform address: one
        xv[r] = *(const float4*)(xbase + (rg * 8 + r) * SD + k0);  // line per read
      #pragma unroll
      for (int r = 0; r < 8; ++r) {
        const int R = rg * 8 + r;
        acc[R].x = fmaf(xv[r].x, w0.x, acc[R].x);
        acc[R].y = fmaf(xv[r].x, w0.y, acc[R].y);
        acc[R].x = fmaf(xv[r].y, w1.x, acc[R].x);
        acc[R].y = fmaf(xv[r].y, w1.y, acc[R].y);
        acc[R].x = fmaf(xv[r].z, w2.x, acc[R].x);
        acc[R].y = fmaf(xv[r].z, w2.y, acc[R].y);
        acc[R].x = fmaf(xv[r].w, w3.x, acc[R].x);
        acc[R].y = fmaf(xv[r].w, w3.y, acc[R].y);
      }
    }
  }

  // bias + relu -> LDS; float4-group g stored at (g ^ (row&7)); lane owns
  // half of group g = wl>>1 (half = wl&1).
  {
    const int g    = wl >> 1;
    const int half = wl & 1;
    v2f bb = ((const v2f*)(ws + B1_OFF))[wl];
    #pragma unroll
    for (int R = 0; R < 16; ++R) {
      v2f hv;
      hv.x = acc[R].x + bb.x; hv.y = acc[R].y + bb.y;
      hv.x = hv.x > 0.0f ? hv.x : 0.0f;
      hv.y = hv.y > 0.0f ? hv.y : 0.0f;
      *(v2f*)&s_h[R][((g ^ (R & 7)) << 2) + half * 2] = hv;
    }
  }
  __syncthreads();

  // ---- layer 2: h2 = relu(h1 @ W2^T + b2), K = 256. Same col-split.
  #pragma unroll
  for (int r = 0; r < 16; ++r) acc[r] = (v2f){0.f, 0.f};

  #pragma unroll 2
  for (int k0 = 0; k0 < HID; k0 += 4) {
    const int wb = k0 * 128 + wl;
    v2f w0 = W2T2[wb];
    v2f w1 = W2T2[wb + 128];
    v2f w2 = W2T2[wb + 256];
    v2f w3 = W2T2[wb + 384];
    #pragma unroll
    for (int rg = 0; rg < 2; ++rg) {
      float4 xv[8];
      #pragma unroll
      for (int r = 0; r < 8; ++r) {                       // uniform LDS address ->
        const int R = rg * 8 + r;                         // HW broadcast, no conflict
        xv[r] = *(const float4*)&s_h[R][(((k0 >> 2) ^ (R & 7)) << 2)];
      }
      #pragma unroll
      for (int r = 0; r < 8; ++r) {
        const int R = rg * 8 + r;
        acc[R].x = fmaf(xv[r].x, w0.x, acc[R].x);
        acc[R].y = fmaf(xv[r].x, w0.y, acc[R].y);
        acc[R].x = fmaf(xv[r].y, w1.x, acc[R].x);
        acc[R].y = fmaf(xv[r].y, w1.y, acc[R].y);
        acc[R].x = fmaf(xv[r].z, w2.x, acc[R].x);
        acc[R].y = fmaf(xv[r].z, w2.y, acc[R].y);
        acc[R].x = fmaf(xv[r].w, w3.x, acc[R].x);
        acc[R].y = fmaf(xv[r].w, w3.y, acc[R].y);
      }
    }
  }
  __syncthreads();   // all h1 reads (both waves) done before overwrite

  // bias + relu -> h2 into the SAME LDS rows
  {
    const int g    = wl >> 1;
    const int half = wl & 1;
    v2f bb = ((const v2f*)(ws + B2_OFF))[wl];
    #pragma unroll
    for (int R = 0; R < 16; ++R) {
      v2f hv;
      hv.x = acc[R].x + bb.x; hv.y = acc[R].y + bb.y;
      hv.x = hv.x > 0.0f ? hv.x : 0.0f;
      hv.y = hv.y > 0.0f ? hv.y : 0.0f;
      *(v2f*)&s_h[R][((g ^ (R & 7)) << 2) + half * 2] = hv;
    }
  }
  __syncthreads();

  // ---- layer 3 (K=256, N=16) + epilogue. This wave: rows wvu*8..wvu*8+7.
  // Lane -> (row = wvu*8 + lane>>3, action = lane&7); u and s chains serial
  // k-ascending (matches sgemm).
  {
    const int key3 = lane >> 3;              // row & 7
    const int r3   = wvu * 8 + key3;
    const int a    = lane & 7;
    const float* __restrict__ h2row = &s_h[r3][0];
    float accu = 0.0f, accs = 0.0f;
    #pragma unroll 2
    for (int k0 = 0; k0 < HID; k0 += 4) {
      const int col = ((k0 >> 2) ^ key3) << 2;        // XOR layout; 8 rows -> 8 banks
      v2f ha = *(const v2f*)(h2row + col);            // k0, k0+1 (8-lane broadcast)
      v2f hb = *(const v2f*)(h2row + col + 2);        // k0+2, k0+3
      v2f wp0 = W3P[(k0 + 0) * 8 + a];
      v2f wp1 = W3P[(k0 + 1) * 8 + a];
      v2f wp2 = W3P[(k0 + 2) * 8 + a];
      v2f wp3 = W3P[(k0 + 3) * 8 + a];
      accu = fmaf(ha.x, wp0.x, accu); accs = fmaf(ha.x, wp0.y, accs);
      accu = fmaf(ha.y, wp1.x, accu); accs = fmaf(ha.y, wp1.y, accs);
      accu = fmaf(hb.x, wp2.x, accu); accs = fmaf(hb.x, wp2.y, accs);
      accu = fmaf(hb.y, wp3.x, accu); accs = fmaf(hb.y, wp3.y, accs);
    }
    v2f b3p = ((const v2f*)(ws + B3P_OFF))[a];
    float nu = accu + b3p.x;
    float ns = accs + b3p.y;

    long grow = brow + r3;
    float sa = fabsf(ns);
    float ev = eps[grow * AD + a];                // coalesced: base + wl
    float t  = __fmul_rn(sa, ev);                 // separately-rounded mul
    float z  = __fadd_rn(nu, t);                  // separately-rounded add
    float e  = (float)exp(-(double)z);            // correctly-rounded expf near boundary
    float d  = __fadd_rn(1.0f, e);
    float act = 1.0f / d;
    float q  = act * 8.0f;                        // exact
    float wq = __fadd_rn(q, 1.0f);
    out[grow * AD + a] = (int)wq;                 // truncation, as astype(int32)
  }
}

extern "C" void kernel_launch(void* const* d_in, const int* in_sizes, int n_in,
                              void* d_out, int out_size, void* d_ws, size_t ws_size,
                              hipStream_t stream) {
  const float* state = (const float*)d_in[0];
  const float* W1    = (const float*)d_in[1];
  const float* b1    = (const float*)d_in[2];
  const float* W2    = (const float*)d_in[3];
  const float* b2    = (const float*)d_in[4];
  const float* W3    = (const float*)d_in[5];
  const float* b3    = (const float*)d_in[6];
  const float* eps   = (const float*)d_in[7];
  int*   out = (int*)d_out;
  float* ws  = (float*)d_ws;   // 411,712 bytes; rebuilt every launch

  hipLaunchKernelGGL(prep_weights, dim3(128), dim3(256), 0, stream,
                     W1, b1, W2, b2, W3, b3, ws);
  hipLaunchKernelGGL(actor_fused, dim3(NB / 16), dim3(128), 0, stream,
                     state, eps, ws, out);
}

// Round 7
// 917.431 us; speedup vs baseline: 1.0159x; 1.0159x over previous
//
#include <hip/hip_runtime.h>
#include <math.h>

// Problem constants
#define NB  262144   // batch
#define SD  128      // STATE_DIM
#define HID 256      // HIDDEN
#define AD  8        // ACTION_DIM

typedef float v2f __attribute__((ext_vector_type(2)));

// d_ws layout (floats)
#define W1T_OFF 0                       // [SD][HID]   W1T[k*HID+j] = W1[j*SD+k]
#define W2T_OFF (SD*HID)                // [HID][HID]  32768
#define W3P_OFF (W2T_OFF + HID*HID)     // [HID][AD] float2 pairs (u,s): 98304, 4096 floats
#define B1_OFF  (W3P_OFF + HID*2*AD)    // 102400
#define B2_OFF  (B1_OFF + HID)          // 102656
#define B3P_OFF (B2_OFF + HID)          // 102912, [AD] float2 pairs
#define WS_FLOATS (B3P_OFF + 2*AD)      // 102928 floats = 411,712 bytes

__global__ __launch_bounds__(256) void prep_weights(
    const float* __restrict__ W1, const float* __restrict__ b1,
    const float* __restrict__ W2, const float* __restrict__ b2,
    const float* __restrict__ W3, const float* __restrict__ b3,
    float* __restrict__ ws) {
  int stride = gridDim.x * blockDim.x;
  for (int i = blockIdx.x * blockDim.x + threadIdx.x; i < WS_FLOATS; i += stride) {
    float v;
    if (i < W2T_OFF) {                       // W1T
      int k = i >> 8, j = i & 255;
      v = W1[j * SD + k];
    } else if (i < W3P_OFF) {                // W2T
      int t = i - W2T_OFF;
      int k = t >> 8, j = t & 255;
      v = W2[j * HID + k];
    } else if (i < B1_OFF) {                 // W3P[k][a] = (W3[a][k], W3[a+8][k])
      int t = i - W3P_OFF;
      int k = t >> 4, a = (t >> 1) & 7, h = t & 1;
      v = W3[(a + 8 * h) * HID + k];
    } else if (i < B2_OFF) {
      v = b1[i - B1_OFF];
    } else if (i < B3P_OFF) {
      v = b2[i - B2_OFF];
    } else {                                 // B3P[a] = (b3[a], b3[a+8])
      int t = i - B3P_OFF;
      v = b3[(t >> 1) + 8 * (t & 1)];
    }
    ws[i] = v;
  }
}

// R10/R11 theory chain (R11 = R10 resubmitted verbatim; the R10 run died in
// container acquire — infrastructure, same as R5/R6):
//  - Invariant across R4..R9: VALUBusy*dur ~ 480-490 us (the work), stall
//    ~320 us never moves. R9 halved L2 weight traffic -> WORSE (863): L2 BW
//    is NOT the stall. Occupancy knobs (R7/R8) were no-ops too.
//  - FETCH_SIZE 137 MB ~= state: state comes from HBM. Layer 1's xv reads
//    are wave-uniform 16B global loads inside the k-loop; one ~900-cyc HBM
//    miss per 128B line (8 k-iters) vs 128 cyc of fma per iter and only
//    ~3.4 waves/SIMD -> layer-1 is HBM-LATENCY serialized.
//  - Fix: stage each wave's 8 rows of x (4 KB) into its own s_h rows UP
//    FRONT with 4 coalesced global_load_dwordx4 + ds_write_b128 (wave-
//    private, no barriers; x lives in cols 0..127 and is fully consumed, in
//    program order, before h1 overwrites the rows). Layer-1 xv reads become
//    uniform LDS broadcasts. Everything else identical to R8 (806 us).
__global__ __launch_bounds__(128, 4) void actor_fused(
    const float* __restrict__ state, const float* __restrict__ eps,
    const float* __restrict__ ws, int* __restrict__ out) {
  __shared__ float s_h[16][256];   // 16,384 B

  const int tid  = threadIdx.x;
  const int lane = tid & 63;
  const int wvu  = __builtin_amdgcn_readfirstlane(tid >> 6);  // 0..1, uniform
  const long wrow = (long)blockIdx.x * 16 + wvu * 8;          // wave's first row

  const float4* __restrict__ W1T4 = (const float4*)(ws + W1T_OFF);  // [SD][64]
  const float4* __restrict__ W2T4 = (const float4*)(ws + W2T_OFF);  // [HID][64]
  const v2f*    __restrict__ W3P  = (const v2f*)(ws + W3P_OFF);     // [HID][8]

  // ---- stage x: this wave's 8 rows (4 KB) -> s_h[wave rows][0..127].
  // Coalesced: 4 x (64 lanes x 16B = 1 KB contiguous). Wave-private rows,
  // consumed before h1 overwrites them -> no barrier needed.
  {
    const float4* __restrict__ xg = (const float4*)(state + wrow * SD);  // 256 chunks
    #pragma unroll
    for (int i = 0; i < 4; ++i) {
      const int ci  = i * 64 + lane;     // 16B-chunk index 0..255
      const int row = ci >> 5;           // 32 chunks per row
      const int c   = ci & 31;
      float4 v = xg[ci];
      *(float4*)&s_h[wvu * 8 + row][c << 2] = v;
    }
  }

  // ---- layer 1: h1 = relu(x @ W1^T + b1), K = 128
  float acc[8][4];
  #pragma unroll
  for (int r = 0; r < 8; ++r)
    #pragma unroll
    for (int c = 0; c < 4; ++c) acc[r][c] = 0.0f;

  #pragma unroll 2
  for (int k0 = 0; k0 < SD; k0 += 4) {
    float4 w[4];
    #pragma unroll
    for (int j = 0; j < 4; ++j) w[j] = W1T4[(k0 + j) * 64 + lane];
    float4 xv[8];
    #pragma unroll
    for (int r = 0; r < 8; ++r)                       // uniform LDS address ->
      xv[r] = *(const float4*)&s_h[wvu * 8 + r][k0];  // HW broadcast, no conflict
    #pragma unroll
    for (int j = 0; j < 4; ++j) {
      #pragma unroll
      for (int r = 0; r < 8; ++r) {
        float x = (j == 0) ? xv[r].x : (j == 1) ? xv[r].y
                : (j == 2) ? xv[r].z : xv[r].w;
        acc[r][0] = fmaf(x, w[j].x, acc[r][0]);
        acc[r][1] = fmaf(x, w[j].y, acc[r][1]);
        acc[r][2] = fmaf(x, w[j].z, acc[r][2]);
        acc[r][3] = fmaf(x, w[j].w, acc[r][3]);
      }
    }
  }

  // bias + relu -> wave-private LDS rows; float4-group g stored at (g ^ r).
  // (x region cols 0..127 is dead now; overwrite is safe in program order.)
  {
    float4 bb = ((const float4*)(ws + B1_OFF))[lane];
    #pragma unroll
    for (int r = 0; r < 8; ++r) {
      float4 hv;
      hv.x = acc[r][0] + bb.x; hv.y = acc[r][1] + bb.y;
      hv.z = acc[r][2] + bb.z; hv.w = acc[r][3] + bb.w;
      hv.x = hv.x > 0.0f ? hv.x : 0.0f;
      hv.y = hv.y > 0.0f ? hv.y : 0.0f;
      hv.z = hv.z > 0.0f ? hv.z : 0.0f;
      hv.w = hv.w > 0.0f ? hv.w : 0.0f;
      *(float4*)&s_h[wvu * 8 + r][(lane ^ r) << 2] = hv;
    }
  }

  // ---- layer 2: h2 = relu(h1 @ W2^T + b2), K = 256
  #pragma unroll
  for (int r = 0; r < 8; ++r)
    #pragma unroll
    for (int c = 0; c < 4; ++c) acc[r][c] = 0.0f;

  #pragma unroll 2
  for (int k0 = 0; k0 < HID; k0 += 4) {
    float4 w[4];
    #pragma unroll
    for (int j = 0; j < 4; ++j) w[j] = W2T4[(k0 + j) * 64 + lane];
    float4 xv[8];
    #pragma unroll
    for (int r = 0; r < 8; ++r)                       // uniform LDS address ->
      xv[r] = *(const float4*)&s_h[wvu * 8 + r][(((k0 >> 2) ^ r) << 2)];  // broadcast
    #pragma unroll
    for (int j = 0; j < 4; ++j) {
      #pragma unroll
      for (int r = 0; r < 8; ++r) {
        float x = (j == 0) ? xv[r].x : (j == 1) ? xv[r].y
                : (j == 2) ? xv[r].z : xv[r].w;
        acc[r][0] = fmaf(x, w[j].x, acc[r][0]);
        acc[r][1] = fmaf(x, w[j].y, acc[r][1]);
        acc[r][2] = fmaf(x, w[j].z, acc[r][2]);
        acc[r][3] = fmaf(x, w[j].w, acc[r][3]);
      }
    }
  }

  // bias + relu -> h2 into the SAME LDS rows (all h1 reads done, program order)
  {
    float4 bb = ((const float4*)(ws + B2_OFF))[lane];
    #pragma unroll
    for (int r = 0; r < 8; ++r) {
      float4 hv;
      hv.x = acc[r][0] + bb.x; hv.y = acc[r][1] + bb.y;
      hv.z = acc[r][2] + bb.z; hv.w = acc[r][3] + bb.w;
      hv.x = hv.x > 0.0f ? hv.x : 0.0f;
      hv.y = hv.y > 0.0f ? hv.y : 0.0f;
      hv.z = hv.z > 0.0f ? hv.z : 0.0f;
      hv.w = hv.w > 0.0f ? hv.w : 0.0f;
      *(float4*)&s_h[wvu * 8 + r][(lane ^ r) << 2] = hv;
    }
  }

  // ---- layer 3 (K=256, N=16) + epilogue. Lane -> (row = lane>>3, action = lane&7),
  // both u and s chains serial k-ascending (matches sgemm).
  {
    const int r3 = lane >> 3;
    const int a  = lane & 7;
    const float* __restrict__ h2row = &s_h[wvu * 8 + r3][0];
    float accu = 0.0f, accs = 0.0f;
    #pragma unroll 2
    for (int k0 = 0; k0 < HID; k0 += 4) {
      const int col = ((k0 >> 2) ^ r3) << 2;          // XOR layout; 8 rows -> 8 banks
      v2f ha = *(const v2f*)(h2row + col);            // k0, k0+1 (8-lane broadcast)
      v2f hb = *(const v2f*)(h2row + col + 2);        // k0+2, k0+3
      v2f wp0 = W3P[(k0 + 0) * 8 + a];
      v2f wp1 = W3P[(k0 + 1) * 8 + a];
      v2f wp2 = W3P[(k0 + 2) * 8 + a];
      v2f wp3 = W3P[(k0 + 3) * 8 + a];
      accu = fmaf(ha.x, wp0.x, accu); accs = fmaf(ha.x, wp0.y, accs);
      accu = fmaf(ha.y, wp1.x, accu); accs = fmaf(ha.y, wp1.y, accs);
      accu = fmaf(hb.x, wp2.x, accu); accs = fmaf(hb.x, wp2.y, accs);
      accu = fmaf(hb.y, wp3.x, accu); accs = fmaf(hb.y, wp3.y, accs);
    }
    v2f b3p = ((const v2f*)(ws + B3P_OFF))[a];
    float nu = accu + b3p.x;
    float ns = accs + b3p.y;

    long grow = wrow + r3;
    float sa = fabsf(ns);
    float ev = eps[grow * AD + a];                // coalesced: base + lane
    float t  = __fmul_rn(sa, ev);                 // separately-rounded mul
    float z  = __fadd_rn(nu, t);                  // separately-rounded add
    float e  = (float)exp(-(double)z);            // correctly-rounded expf near boundary
    float d  = __fadd_rn(1.0f, e);
    float act = 1.0f / d;
    float q  = act * 8.0f;                        // exact
    float wq = __fadd_rn(q, 1.0f);
    out[grow * AD + a] = (int)wq;                 // truncation, as astype(int32)
  }
}

extern "C" void kernel_launch(void* const* d_in, const int* in_sizes, int n_in,
                              void* d_out, int out_size, void* d_ws, size_t ws_size,
                              hipStream_t stream) {
  const float* state = (const float*)d_in[0];
  const float* W1    = (const float*)d_in[1];
  const float* b1    = (const float*)d_in[2];
  const float* W2    = (const float*)d_in[3];
  const float* b2    = (const float*)d_in[4];
  const float* W3    = (const float*)d_in[5];
  const float* b3    = (const float*)d_in[6];
  const float* eps   = (const float*)d_in[7];
  int*   out = (int*)d_out;
  float* ws  = (float*)d_ws;   // 411,712 bytes; rebuilt every launch

  hipLaunchKernelGGL(prep_weights, dim3(128), dim3(256), 0, stream,
                     W1, b1, W2, b2, W3, b3, ws);
  hipLaunchKernelGGL(actor_fused, dim3(NB / 16), dim3(128), 0, stream,
                     state, eps, ws, out);
}